// Round 7
// baseline (272.562 us; speedup 1.0000x reference)
//
#include <hip/hip_runtime.h>
#include <hip/hip_bf16.h>

typedef unsigned short ushort_t;
typedef __bf16 bf16x8 __attribute__((ext_vector_type(8)));
typedef float f32x4 __attribute__((ext_vector_type(4)));

#define BM 128
#define BN 128
#define BK 64

__device__ __forceinline__ float bf2f(ushort_t u) {
    union { unsigned int i; float f; } x; x.i = ((unsigned int)u) << 16; return x.f;
}
__device__ __forceinline__ ushort_t f2bf(float f) {
    __hip_bfloat16 h = __float2bfloat16(f);
    return *(ushort_t*)&h;
}
__device__ __forceinline__ unsigned int fbits(float f) {
    union { float f; unsigned int u; } x; x.f = f; return x.u;
}
__device__ __forceinline__ void async16(const void* g, void* l) {
    __builtin_amdgcn_global_load_lds((const __attribute__((address_space(1))) void*)g,
                                     (__attribute__((address_space(3))) void*)l, 16, 0, 0);
}

// ---- pack weights: [0,1024): W_in -> Wpt (scaled by Bv); [1024,2048): C -> Ct ----
// Packed B-fragment layout (mfma_16x16x32 B-op): element (n,k) at
//   (((n>>4)*32 + (k>>5))*64 + ((k>>3)&3)*16 + (n&15))*8 + (k&7)
__global__ void pack_weights(const float* __restrict__ W_in, const float* __restrict__ C,
                             const float* __restrict__ Bv,
                             __hip_bfloat16* __restrict__ Wpt, __hip_bfloat16* __restrict__ Ct) {
    int bid = blockIdx.x;
    __shared__ float tile[32][33];
    const float* in;
    __hip_bfloat16* out;
    bool do_scale;
    int lid;
    if (bid < 1024) { lid = bid;        in = W_in; out = Wpt; do_scale = true; }
    else            { lid = bid - 1024; in = C;    out = Ct;  do_scale = false; }
    int bx = (lid & 31) * 32;   // n base
    int by = (lid >> 5) * 32;   // k base
    int tx = threadIdx.x & 31, ty = threadIdx.x >> 5;  // ty 0..7
    #pragma unroll
    for (int i = 0; i < 32; i += 8)
        tile[ty + i][tx] = in[(size_t)(by + ty + i) * 1024 + bx + tx];
    __syncthreads();
    if (threadIdx.x < 128) {
        int n_local = threadIdx.x & 31;
        int quad    = threadIdx.x >> 5;          // 0..3 = (k>>3)&3
        int n = bx + n_local;
        float s = do_scale ? Bv[n] : 1.0f;
        int lr     = n & 15;
        int n_tile = n >> 4;
        int k_tile = by >> 5;
        ushort_t buf[8];
        #pragma unroll
        for (int j = 0; j < 8; ++j)
            buf[j] = f2bf(tile[quad * 8 + j][n_local] * s);
        size_t off = (((size_t)n_tile * 32 + k_tile) * 64 + quad * 16 + lr) * 8;
        ushort_t* dst = (ushort_t*)out + off;
        *(ushort4*)dst       = *(ushort4*)&buf[0];
        *(ushort4*)(dst + 4) = *(ushort4*)&buf[4];
    }
}

// ---- GEMM, XCD swizzle, B direct from global packed-fragment (L2-resident). ----
// EPI=0: A = x in FP32, staged via async16 + fp32 XOR swizzle, truncated to bf16
//        in-register (v_perm). out_bf[m][n] = bf16(acc + b_in[n]*Bv[n]) via LDS-
//        coalesced stores.
// EPI=1: A = hbuf bf16 (R3-verified staging). out_f = acc + x[m][n]*Dvec[n].
template <int EPI>
__global__ __launch_bounds__(256) void gemm_bt(
    const void* __restrict__ Ag, const __hip_bfloat16* __restrict__ Bpk,
    int M, int N, int K,
    const float* __restrict__ b_in, const float* __restrict__ Bv,
    __hip_bfloat16* __restrict__ out_bf,
    const float* __restrict__ xres_f, const float* __restrict__ Dvec,
    float* __restrict__ out_f) {
    const int tid  = threadIdx.x;
    const int wave = tid >> 6;
    const int lane = tid & 63;
    const int quad = lane >> 4;
    const int lr   = lane & 15;
    const int wm   = wave >> 1;   // 0..1
    const int wn   = wave & 1;    // 0..1

    // XCD-aware swizzle: each XCD owns a contiguous 16-m-block stripe x 8 n-blocks.
    const int lin   = blockIdx.y * gridDim.x + blockIdx.x;   // 0..1023
    const int xcd   = lin & 7;
    const int local = lin >> 3;                               // 0..127
    const int m_blk = xcd * 16 + (local >> 3);                // 0..127
    const int n_blk = local & 7;                              // 0..7
    const int m0 = m_blk * BM;
    const int n0 = n_blk * BN;

    // EPI=0: 32 KB fp32 A-tile; EPI=1: 16 KB bf16 A-tile. Reused by epilogue.
    __shared__ __align__(16) ushort_t sA[EPI == 0 ? BM * BK * 2 : BM * BK];

    const ushort_t* Bp = (const ushort_t*)Bpk;
    const int ktiles = K >> 5;
    const int ntile0 = n0 >> 4;

    f32x4 acc[4][4];
    #pragma unroll
    for (int i = 0; i < 4; ++i)
        #pragma unroll
        for (int j = 0; j < 4; ++j)
            #pragma unroll
            for (int r = 0; r < 4; ++r) acc[i][j][r] = 0.0f;

    if constexpr (EPI == 0) {
        // ---------- FP32-A path ----------
        const float* Af = (const float*)Ag;
        float* sAf = (float*)sA;
        const int g4 = lane >> 4;    // row within 4-row chunk group
        const int ph = lane & 15;    // physical 16B-chunk slot this lane fills
        for (int k0 = 0; k0 < K; k0 += BK) {
            __syncthreads();
            #pragma unroll
            for (int j = 0; j < 8; ++j) {
                int c = j * 4 + wave;            // wave-uniform chunk-group 0..31
                int row = c * 4 + g4;            // local row 0..127
                // phys slot ph of row r holds logical chunk l = ph ^ (r&15)
                int lcol = (ph ^ (((c & 3) << 2) | g4)) << 2;   // float col
                const float* gA = Af + (size_t)(m0 + row) * K + k0 + lcol;
                async16(gA, &sAf[c * 256]);
            }
            __syncthreads();
            #pragma unroll
            for (int kk = 0; kk < BK; kk += 32) {
                const int kt = (k0 + kk) >> 5;
                bf16x8 bfr[4];
                #pragma unroll
                for (int j = 0; j < 4; ++j)
                    bfr[j] = *(const bf16x8*)&Bp[((((size_t)(ntile0 + wn * 4 + j)) * ktiles + kt) * 64 + lane) * 8];
                const int l0 = (kk >> 2) + quad * 2;   // logical chunk of k-start
                bf16x8 af[4];
                #pragma unroll
                for (int i = 0; i < 4; ++i) {
                    int rL = wm * 64 + i * 16 + lr;
                    int sw = rL & 15;
                    float4 v0 = *(const float4*)&sAf[rL * 64 + ((l0 ^ sw) << 2)];
                    float4 v1 = *(const float4*)&sAf[rL * 64 + (((l0 + 1) ^ sw) << 2)];
                    union { unsigned int u[4]; bf16x8 v; } pk;
                    pk.u[0] = __builtin_amdgcn_perm(fbits(v0.y), fbits(v0.x), 0x07060302);
                    pk.u[1] = __builtin_amdgcn_perm(fbits(v0.w), fbits(v0.z), 0x07060302);
                    pk.u[2] = __builtin_amdgcn_perm(fbits(v1.y), fbits(v1.x), 0x07060302);
                    pk.u[3] = __builtin_amdgcn_perm(fbits(v1.w), fbits(v1.z), 0x07060302);
                    af[i] = pk.v;
                }
                #pragma unroll
                for (int i = 0; i < 4; ++i)
                    #pragma unroll
                    for (int j = 0; j < 4; ++j)
                        acc[i][j] = __builtin_amdgcn_mfma_f32_16x16x32_bf16(af[i], bfr[j], acc[i][j], 0, 0, 0);
            }
        }
    } else {
        // ---------- BF16-A path (R3/R6-verified) ----------
        const ushort_t* A = (const ushort_t*)Ag;
        const int row8 = lane >> 3;
        const int schunk = (lane & 7) ^ row8;
        const int ldcol = schunk * 8;
        for (int k0 = 0; k0 < K; k0 += BK) {
            __syncthreads();
            #pragma unroll
            for (int j = 0; j < 4; ++j) {
                int c = j * 4 + wave;
                int row = c * 8 + row8;
                const ushort_t* gA = A + (size_t)(m0 + row) * K + k0 + ldcol;
                async16(gA, &sA[c * 512]);
            }
            __syncthreads();
            #pragma unroll
            for (int kk = 0; kk < BK; kk += 32) {
                const int kt = (k0 + kk) >> 5;
                bf16x8 bfr[4];
                #pragma unroll
                for (int j = 0; j < 4; ++j)
                    bfr[j] = *(const bf16x8*)&Bp[((((size_t)(ntile0 + wn * 4 + j)) * ktiles + kt) * 64 + lane) * 8];
                const int ck = (kk >> 3) + quad;
                const int pc = (ck ^ (lr & 7)) * 8;
                bf16x8 af[4];
                #pragma unroll
                for (int i = 0; i < 4; ++i)
                    af[i] = *(const bf16x8*)&sA[(wm * 64 + i * 16 + lr) * BK + pc];
                #pragma unroll
                for (int i = 0; i < 4; ++i)
                    #pragma unroll
                    for (int j = 0; j < 4; ++j)
                        acc[i][j] = __builtin_amdgcn_mfma_f32_16x16x32_bf16(af[i], bfr[j], acc[i][j], 0, 0, 0);
            }
        }
    }

    // epilogue: C/D layout col=lane&15, row=quad*4+reg
    if constexpr (EPI == 0) {
        // coalesced bf16 stores via LDS (reuse sA), row stride 136 elems
        ushort_t* st = sA;
        #pragma unroll
        for (int i = 0; i < 4; ++i) {
            __syncthreads();
            #pragma unroll
            for (int j = 0; j < 4; ++j) {
                int colL = wn * 64 + j * 16 + lr;
                float bs = b_in[n0 + colL] * Bv[n0 + colL];
                #pragma unroll
                for (int r = 0; r < 4; ++r) {
                    int r32 = wm * 16 + quad * 4 + r;
                    st[r32 * 136 + colL] = f2bf(acc[i][j][r] + bs);
                }
            }
            __syncthreads();
            int r32 = tid >> 3;
            int cch = (tid & 7) * 16;
            int row_g = m0 + (r32 >> 4) * 64 + i * 16 + (r32 & 15);
            bf16x8 v0 = *(const bf16x8*)&st[r32 * 136 + cch];
            bf16x8 v1 = *(const bf16x8*)&st[r32 * 136 + cch + 8];
            ushort_t* dst = (ushort_t*)out_bf + (size_t)row_g * N + n0 + cch;
            *(bf16x8*)dst       = v0;
            *(bf16x8*)(dst + 8) = v1;
        }
    } else {
        #pragma unroll
        for (int i = 0; i < 4; ++i) {
            int row = m0 + wm * 64 + i * 16 + quad * 4;
            #pragma unroll
            for (int j = 0; j < 4; ++j) {
                int col = n0 + wn * 64 + j * 16 + lr;
                float dv = Dvec[col];
                #pragma unroll
                for (int r = 0; r < 4; ++r) {
                    float xv = xres_f[(size_t)(row + r) * N + col];
                    out_f[(size_t)(row + r) * N + col] = acc[i][j][r] + xv * dv;
                }
            }
        }
    }
}

// ---- scan v3: h_t = a*h_{t-1} + b_t, bf16 in/out. 4 ch/thread (ushort4,
// 512 B per wave-op), SCH=16 -> 1024 blocks, 48 serial steps/thread.
// Warm-up (exact to fp32: |a|^32 ~ 1e-14) in groups of 4 independent loads.
#define SCH 16
#define SWARM 32
__global__ void scan_kernel(const __hip_bfloat16* __restrict__ b, __hip_bfloat16* __restrict__ h,
                            const float* __restrict__ logA, int T, int DD) {
    int c0 = threadIdx.x * 4;          // 4 channels per thread
    int q  = blockIdx.x;               // chunk index
    int bb = blockIdx.y;               // batch
    float4 la = *(const float4*)(logA + c0);
    float a1[4] = { -__expf(la.x), -__expf(la.y), -__expf(la.z), -__expf(la.w) };
    float a2[4], a3[4], a4[4];
    #pragma unroll
    for (int j = 0; j < 4; ++j) { a2[j] = a1[j] * a1[j]; a3[j] = a2[j] * a1[j]; a4[j] = a2[j] * a2[j]; }
    int ts = q * SCH;
    int t0 = ts - SWARM; if (t0 < 0) t0 = 0;
    int w = ts - t0;                   // 0, 16, or 32 (multiple of 4)
    size_t base = (size_t)bb * T * DD + c0;
    const ushort_t* bp = (const ushort_t*)b + base + (size_t)t0 * DD;
    float hh[4] = { 0.f, 0.f, 0.f, 0.f };
    for (int t = 0; t < w; t += 4) {
        ushort_t v0[4], v1[4], v2[4], v3[4];
        *(ushort4*)v0 = *(const ushort4*)(bp);
        *(ushort4*)v1 = *(const ushort4*)(bp + DD);
        *(ushort4*)v2 = *(const ushort4*)(bp + 2 * (size_t)DD);
        *(ushort4*)v3 = *(const ushort4*)(bp + 3 * (size_t)DD);
        bp += 4 * (size_t)DD;
        #pragma unroll
        for (int j = 0; j < 4; ++j) {
            float s = fmaf(a3[j], bf2f(v0[j]),
                      fmaf(a2[j], bf2f(v1[j]),
                      fmaf(a1[j], bf2f(v2[j]), bf2f(v3[j]))));
            hh[j] = fmaf(a4[j], hh[j], s);
        }
    }
    ushort_t* hp = (ushort_t*)h + base + (size_t)ts * DD;
    #pragma unroll
    for (int t = 0; t < SCH; ++t) {
        ushort_t vv[4], oo[4];
        *(ushort4*)vv = *(const ushort4*)bp; bp += DD;
        #pragma unroll
        for (int j = 0; j < 4; ++j) {
            hh[j] = fmaf(a1[j], hh[j], bf2f(vv[j]));
            oo[j] = f2bf(hh[j]);
        }
        *(ushort4*)hp = *(ushort4*)oo; hp += DD;
    }
}

extern "C" void kernel_launch(void* const* d_in, const int* in_sizes, int n_in,
                              void* d_out, int out_size, void* d_ws, size_t ws_size,
                              hipStream_t stream) {
    const float* x    = (const float*)d_in[0];
    const float* W_in = (const float*)d_in[1];
    const float* b_in = (const float*)d_in[2];
    const float* logA = (const float*)d_in[3];
    const float* Bv   = (const float*)d_in[4];
    const float* C    = (const float*)d_in[5];
    const float* Dv   = (const float*)d_in[6];
    float* out = (float*)d_out;

    const int Bsz = 8, T = 2048, d = 1024;
    const int M = Bsz * T;  // 16384

    // workspace carve (~68 MB)
    char* w = (char*)d_ws;
    __hip_bfloat16* Wpt  = (__hip_bfloat16*)w;                 //  2 MB (packed)
    __hip_bfloat16* Ct   = Wpt + (size_t)d * d;                //  2 MB (packed)
    __hip_bfloat16* bbuf = Ct + (size_t)d * d;                 // 32 MB
    __hip_bfloat16* hbuf = bbuf + (size_t)M * d;               // 32 MB

    pack_weights<<<2048, 256, 0, stream>>>(W_in, C, Bv, Wpt, Ct);

    gemm_bt<0><<<dim3(d / BN, M / BM), 256, 0, stream>>>(
        (const void*)x, Wpt, M, d, d, b_in, Bv, bbuf, nullptr, nullptr, nullptr);
    scan_kernel<<<dim3(T / SCH, Bsz), 256, 0, stream>>>(bbuf, hbuf, logA, T, d);
    gemm_bt<1><<<dim3(d / BN, M / BM), 256, 0, stream>>>(
        (const void*)hbuf, Ct, M, d, d, nullptr, nullptr, nullptr, x, Dv, out);
}

// Round 8
// 241.339 us; speedup vs baseline: 1.1294x; 1.1294x over previous
//
#include <hip/hip_runtime.h>
#include <hip/hip_bf16.h>

typedef unsigned short ushort_t;
typedef __bf16 bf16x8 __attribute__((ext_vector_type(8)));
typedef float f32x4 __attribute__((ext_vector_type(4)));

#define BM 128
#define BN 128
#define BK 64

__device__ __forceinline__ float bf2f(ushort_t u) {
    union { unsigned int i; float f; } x; x.i = ((unsigned int)u) << 16; return x.f;
}
__device__ __forceinline__ ushort_t f2bf(float f) {
    __hip_bfloat16 h = __float2bfloat16(f);
    return *(ushort_t*)&h;
}
__device__ __forceinline__ void async16(const void* g, void* l) {
    __builtin_amdgcn_global_load_lds((const __attribute__((address_space(1))) void*)g,
                                     (__attribute__((address_space(3))) void*)l, 16, 0, 0);
}

// ---- fused prep ----
// blocks [0,16384): x fp32->bf16; [16384,17408): W_in->Wpt packed*Bv; [17408,18432): C->Ct packed
// Packed B-fragment layout (mfma_16x16x32 B-op): element (n,k) at
//   (((n>>4)*32 + (k>>5))*64 + ((k>>3)&3)*16 + (n&15))*8 + (k&7)
__global__ void prep_fused(const float* __restrict__ x, const float* __restrict__ W_in,
                           const float* __restrict__ C, const float* __restrict__ Bv,
                           __hip_bfloat16* __restrict__ xb, __hip_bfloat16* __restrict__ Wpt,
                           __hip_bfloat16* __restrict__ Ct) {
    int bid = blockIdx.x;
    if (bid < 16384) {
        size_t idx = ((size_t)bid * 256 + threadIdx.x) * 4;
        float4 v = *(const float4*)(x + idx);
        ushort4 ov;
        ov.x = f2bf(v.x); ov.y = f2bf(v.y); ov.z = f2bf(v.z); ov.w = f2bf(v.w);
        *(ushort4*)((ushort_t*)xb + idx) = ov;
        return;
    }
    __shared__ float tile[32][33];
    const float* in;
    __hip_bfloat16* out;
    bool do_scale;
    int lid;
    if (bid < 17408) { lid = bid - 16384; in = W_in; out = Wpt; do_scale = true; }
    else             { lid = bid - 17408; in = C;    out = Ct;  do_scale = false; }
    int bx = (lid & 31) * 32;   // n base
    int by = (lid >> 5) * 32;   // k base
    int tx = threadIdx.x & 31, ty = threadIdx.x >> 5;
    #pragma unroll
    for (int i = 0; i < 32; i += 8)
        tile[ty + i][tx] = in[(size_t)(by + ty + i) * 1024 + bx + tx];
    __syncthreads();
    if (threadIdx.x < 128) {
        int n_local = threadIdx.x & 31;
        int quad    = threadIdx.x >> 5;          // (k>>3)&3
        int n = bx + n_local;
        float s = do_scale ? Bv[n] : 1.0f;
        int lr     = n & 15;
        int n_tile = n >> 4;
        int k_tile = by >> 5;
        ushort_t buf[8];
        #pragma unroll
        for (int j = 0; j < 8; ++j)
            buf[j] = f2bf(tile[quad * 8 + j][n_local] * s);
        size_t off = (((size_t)n_tile * 32 + k_tile) * 64 + quad * 16 + lr) * 8;
        ushort_t* dst = (ushort_t*)out + off;
        *(ushort4*)dst       = *(ushort4*)&buf[0];
        *(ushort4*)(dst + 4) = *(ushort4*)&buf[4];
    }
}

// ---- GEMM1 + fused scan: computes u rows [m0-32, m0+128) (warm-up + output),
// scans h_t = a*h_{t-1} + u_t*Bv in LDS, writes h rows [m0, m0+128) bf16.
// A = xb bf16 via LDS (R3-verified XOR-swizzle staging, 160 rows);
// B = Wpt packed fragments direct from global (L2-resident).
__global__ __launch_bounds__(256) void gemm1_scan(
    const __hip_bfloat16* __restrict__ Ab, const __hip_bfloat16* __restrict__ Bpk,
    const float* __restrict__ b_in, const float* __restrict__ Bv,
    const float* __restrict__ logA,
    __hip_bfloat16* __restrict__ hout, int M, int N, int K) {
    const int tid  = threadIdx.x;
    const int wave = tid >> 6;
    const int lane = tid & 63;
    const int quad = lane >> 4;
    const int lr   = lane & 15;
    const int wm   = wave >> 1;
    const int wn   = wave & 1;

    const int lin   = blockIdx.y * gridDim.x + blockIdx.x;
    const int xcd   = lin & 7;
    const int local = lin >> 3;
    const int m_blk = xcd * 16 + (local >> 3);
    const int n_blk = local & 7;
    const int m0 = m_blk * BM;
    const int n0 = n_blk * BN;

    // staging uses first 160*64 = 10240 ushorts; epilogue uses 160*136 = 21760
    __shared__ __align__(16) ushort_t sBuf[160 * 136];  // 43.5 KB

    const ushort_t* A  = (const ushort_t*)Ab;
    const ushort_t* Bp = (const ushort_t*)Bpk;
    const int ktiles = K >> 5;
    const int ntile0 = n0 >> 4;

    f32x4 acc[5][4];
    #pragma unroll
    for (int i = 0; i < 5; ++i)
        #pragma unroll
        for (int j = 0; j < 4; ++j)
            #pragma unroll
            for (int r = 0; r < 4; ++r) acc[i][j][r] = 0.0f;

    const int row8 = lane >> 3;
    const int schunk = (lane & 7) ^ row8;
    const int ldcol = schunk * 8;
    for (int k0 = 0; k0 < K; k0 += BK) {
        __syncthreads();
        #pragma unroll
        for (int j = 0; j < 5; ++j) {
            int c = j * 4 + wave;            // chunk 0..19 (8 rows each)
            int row = c * 8 + row8;          // local row 0..159
            int grow = m0 - 32 + row;        // global row (warm-up offset)
            if (grow < 0) grow = 0;          // clamp: only m0==0; values ignored
            const ushort_t* gA = A + (size_t)grow * K + k0 + ldcol;
            async16(gA, &sBuf[c * 512]);
        }
        __syncthreads();
        #pragma unroll
        for (int kk = 0; kk < BK; kk += 32) {
            const int kt = (k0 + kk) >> 5;
            bf16x8 bfr[4];
            #pragma unroll
            for (int j = 0; j < 4; ++j)
                bfr[j] = *(const bf16x8*)&Bp[((((size_t)(ntile0 + wn * 4 + j)) * ktiles + kt) * 64 + lane) * 8];
            const int ck = (kk >> 3) + quad;
            const int pc = (ck ^ (lr & 7)) * 8;
            bf16x8 af[5];
            #pragma unroll
            for (int i = 0; i < 5; ++i)
                af[i] = *(const bf16x8*)&sBuf[(wm * 80 + i * 16 + lr) * BK + pc];
            #pragma unroll
            for (int i = 0; i < 5; ++i)
                #pragma unroll
                for (int j = 0; j < 4; ++j)
                    acc[i][j] = __builtin_amdgcn_mfma_f32_16x16x32_bf16(af[i], bfr[j], acc[i][j], 0, 0, 0);
        }
    }

    // ---- epilogue: u+bias -> LDS (stride 136), in-LDS scan, coalesced h write ----
    __syncthreads();
    #pragma unroll
    for (int i = 0; i < 5; ++i)
        #pragma unroll
        for (int j = 0; j < 4; ++j) {
            int colL = wn * 64 + j * 16 + lr;
            float bs = b_in[n0 + colL] * Bv[n0 + colL];
            #pragma unroll
            for (int r = 0; r < 4; ++r) {
                int slot = wm * 80 + i * 16 + quad * 4 + r;   // 0..159
                sBuf[slot * 136 + colL] = f2bf(acc[i][j][r] + bs);
            }
        }
    __syncthreads();
    if (tid < 128) {
        float a = -__expf(logA[n0 + tid]);
        float h = 0.f;
        int s = ((m0 & 2047) == 0) ? 32 : 0;   // batch start: no warm-up
        for (; s < 32; ++s)
            h = fmaf(a, h, bf2f(sBuf[s * 136 + tid]));
        #pragma unroll 4
        for (int t = 32; t < 160; ++t) {
            h = fmaf(a, h, bf2f(sBuf[t * 136 + tid]));
            sBuf[t * 136 + tid] = f2bf(h);
        }
    }
    __syncthreads();
    #pragma unroll
    for (int i = 0; i < 4; ++i) {
        int r32 = tid >> 3;              // 0..31
        int cch = (tid & 7) * 16;        // 0..112
        int slot = 32 + i * 32 + r32;
        bf16x8 v0 = *(const bf16x8*)&sBuf[slot * 136 + cch];
        bf16x8 v1 = *(const bf16x8*)&sBuf[slot * 136 + cch + 8];
        ushort_t* dst = (ushort_t*)hout + (size_t)(m0 + i * 32 + r32) * N + n0 + cch;
        *(bf16x8*)dst       = v0;
        *(bf16x8*)(dst + 8) = v1;
    }
}

// ---- GEMM2 (R6-verified config): A = hbuf bf16 via LDS, B = Ct packed direct,
// out_f[m][n] = acc + bf2f(xb[m][n])*Dvec[n] ----
__global__ __launch_bounds__(256) void gemm2(
    const __hip_bfloat16* __restrict__ Ab, const __hip_bfloat16* __restrict__ Bpk,
    const __hip_bfloat16* __restrict__ xres_bf, const float* __restrict__ Dvec,
    float* __restrict__ out_f, int M, int N, int K) {
    const int tid  = threadIdx.x;
    const int wave = tid >> 6;
    const int lane = tid & 63;
    const int quad = lane >> 4;
    const int lr   = lane & 15;
    const int wm   = wave >> 1;
    const int wn   = wave & 1;

    const int lin   = blockIdx.y * gridDim.x + blockIdx.x;
    const int xcd   = lin & 7;
    const int local = lin >> 3;
    const int m_blk = xcd * 16 + (local >> 3);
    const int n_blk = local & 7;
    const int m0 = m_blk * BM;
    const int n0 = n_blk * BN;

    __shared__ __align__(16) ushort_t sA[BM * BK];  // 16 KB

    const ushort_t* A  = (const ushort_t*)Ab;
    const ushort_t* Bp = (const ushort_t*)Bpk;
    const int ktiles = K >> 5;
    const int ntile0 = n0 >> 4;

    f32x4 acc[4][4];
    #pragma unroll
    for (int i = 0; i < 4; ++i)
        #pragma unroll
        for (int j = 0; j < 4; ++j)
            #pragma unroll
            for (int r = 0; r < 4; ++r) acc[i][j][r] = 0.0f;

    const int row8 = lane >> 3;
    const int schunk = (lane & 7) ^ row8;
    const int ldcol = schunk * 8;
    for (int k0 = 0; k0 < K; k0 += BK) {
        __syncthreads();
        #pragma unroll
        for (int j = 0; j < 4; ++j) {
            int c = j * 4 + wave;
            int row = c * 8 + row8;
            const ushort_t* gA = A + (size_t)(m0 + row) * K + k0 + ldcol;
            async16(gA, &sA[c * 512]);
        }
        __syncthreads();
        #pragma unroll
        for (int kk = 0; kk < BK; kk += 32) {
            const int kt = (k0 + kk) >> 5;
            bf16x8 bfr[4];
            #pragma unroll
            for (int j = 0; j < 4; ++j)
                bfr[j] = *(const bf16x8*)&Bp[((((size_t)(ntile0 + wn * 4 + j)) * ktiles + kt) * 64 + lane) * 8];
            const int ck = (kk >> 3) + quad;
            const int pc = (ck ^ (lr & 7)) * 8;
            bf16x8 af[4];
            #pragma unroll
            for (int i = 0; i < 4; ++i)
                af[i] = *(const bf16x8*)&sA[(wm * 64 + i * 16 + lr) * BK + pc];
            #pragma unroll
            for (int i = 0; i < 4; ++i)
                #pragma unroll
                for (int j = 0; j < 4; ++j)
                    acc[i][j] = __builtin_amdgcn_mfma_f32_16x16x32_bf16(af[i], bfr[j], acc[i][j], 0, 0, 0);
        }
    }

    #pragma unroll
    for (int i = 0; i < 4; ++i) {
        int row = m0 + wm * 64 + i * 16 + quad * 4;
        #pragma unroll
        for (int j = 0; j < 4; ++j) {
            int col = n0 + wn * 64 + j * 16 + lr;
            float dv = Dvec[col];
            #pragma unroll
            for (int r = 0; r < 4; ++r) {
                float xv = bf2f(((const ushort_t*)xres_bf)[(size_t)(row + r) * N + col]);
                out_f[(size_t)(row + r) * N + col] = acc[i][j][r] + xv * dv;
            }
        }
    }
}

extern "C" void kernel_launch(void* const* d_in, const int* in_sizes, int n_in,
                              void* d_out, int out_size, void* d_ws, size_t ws_size,
                              hipStream_t stream) {
    const float* x    = (const float*)d_in[0];
    const float* W_in = (const float*)d_in[1];
    const float* b_in = (const float*)d_in[2];
    const float* logA = (const float*)d_in[3];
    const float* Bv   = (const float*)d_in[4];
    const float* C    = (const float*)d_in[5];
    const float* Dv   = (const float*)d_in[6];
    float* out = (float*)d_out;

    const int Bsz = 8, T = 2048, d = 1024;
    const int M = Bsz * T;  // 16384

    // workspace carve (~68 MB)
    char* w = (char*)d_ws;
    __hip_bfloat16* xb   = (__hip_bfloat16*)w;                 // 32 MB
    __hip_bfloat16* Wpt  = xb + (size_t)M * d;                 //  2 MB (packed)
    __hip_bfloat16* Ct   = Wpt + (size_t)d * d;                //  2 MB (packed)
    __hip_bfloat16* hbuf = Ct + (size_t)d * d;                 // 32 MB

    prep_fused<<<16384 + 2048, 256, 0, stream>>>(x, W_in, C, Bv, xb, Wpt, Ct);

    gemm1_scan<<<dim3(d / BN, M / BM), 256, 0, stream>>>(
        xb, Wpt, b_in, Bv, logA, hbuf, M, d, d);
    gemm2<<<dim3(d / BN, M / BM), 256, 0, stream>>>(
        hbuf, Ct, xb, Dv, out, M, d, d);
}